// Round 7
// baseline (291.962 us; speedup 1.0000x reference)
//
#include <hip/hip_runtime.h>
#include <hip/hip_bf16.h>

// NonLocalBlock B=4,C=256,H=W=64 (N=4096) — round 11.
//  Mechanism this round: K never touches LDS. qkv stores K in c-chunked
//  K8[c>>3][j][c&7] (mirror of V8); attn producers load K fragments
//  directly to registers as coalesced 1KB instructions. Deletes per window:
//  32 global_load_lds + 32KB LDS staging writes + 64 ds_read_b128 frag
//  reads (~1000 cy/window of LDS port) at the cost of +512 L2-hit lines
//  (ni-twin duplication) and ~200cy single-buffer K-load exposure.
//  Pipeline shifts one window (QK(t) in-window; consumer eats P/V(t-1)).
//  Prologue/epilogue unchanged, now on a plain 64KB scratch union.
// ws = K8 | V8 | W8 = 17.3 MiB.

typedef __attribute__((ext_vector_type(4))) short s16x4;
typedef __attribute__((ext_vector_type(8))) short s16x8;
typedef __attribute__((ext_vector_type(16))) float f32x16;

#define MFMA32(a, b, c) __builtin_amdgcn_mfma_f32_32x32x16_bf16((a), (b), (c), 0, 0, 0)

constexpr int Cc = 256;
constexpr int Nn = 4096;

__device__ inline short f2bf(float f) {
    unsigned int u = __builtin_bit_cast(unsigned int, f);
    u = (u + 0x7fffu + ((u >> 16) & 1u)) >> 16;   // RNE
    return (short)u;
}

// 32x32x16 bf16 MFMA layouts (m74/m101-verified C/D; A/B symmetric k-map):
//   A[m=lane&31][k=(lane>>5)*8+j]   B[k=(lane>>5)*8+j][n=lane&31]
//   C/D: col=lane&31, row=(r&3)+8*(r>>2)+4*(lane>>5)

// W8 chunked fragment: row in [0,256), kc = chunk index (8 k elems each)
#define WFRAG(Wm, row, kc) (*(const s16x8*)&(Wm)[(size_t)(kc)*2048 + (size_t)(row)*8])

// ---------------------------------------------------------------- wcvt
// fp32 [o][c] -> bf16 chunked W8[c>>3][o][c&7]
__global__ __launch_bounds__(256, 4) void wcvt_kernel(
    const float* __restrict__ wq, const float* __restrict__ wk,
    const float* __restrict__ wv, const float* __restrict__ wp,
    short* __restrict__ W)
{
    const int m = blockIdx.y;
    const float* src = (m == 0) ? wq : (m == 1) ? wk : (m == 2) ? wv : wp;
    const int idx = (blockIdx.x * 256 + threadIdx.x) * 8;
    const int o = idx >> 8, c0 = idx & 255;
    float4 a = *(const float4*)(src + idx);
    float4 b = *(const float4*)(src + idx + 4);
    s16x8 p = { f2bf(a.x), f2bf(a.y), f2bf(a.z), f2bf(a.w),
                f2bf(b.x), f2bf(b.y), f2bf(b.z), f2bf(b.w) };
    *(s16x8*)(W + m * 65536 + ((size_t)(c0 >> 3) * 256 + o) * 8) = p;
}

// ---------------------------------------------------------------- qkv (K,V only)
// grid (64 n-tiles, 4 b, 2 mat), 256 thr. LDS xT tile 33.8 KB -> 4 blocks/CU.
// K store NOW chunked K8[c>>3][j][c&7] (j = spatial n, c = out channel).
__global__ __launch_bounds__(256, 4) void qkv_kernel(
    const float* __restrict__ x, const short* __restrict__ W,
    const float* __restrict__ bk, const float* __restrict__ bv,
    short* __restrict__ KT, short* __restrict__ V)
{
    const int nt = blockIdx.x, b = blockIdx.y, mat = blockIdx.z;  // 0=K 1=V
    const int n0 = nt * 64;
    const short* Wm = W + (mat + 1) * 65536;       // Wk at slot 1, Wv at slot 2
    const float* bias = (mat == 0) ? bk : bv;
    const int t = threadIdx.x, lane = t & 63, wid = t >> 6, h = lane >> 5, l31 = lane & 31;

    __shared__ alignas(16) short xT[64][264];      // x^T tile [n][c] bf16

    const float* xb = x + (size_t)b * Cc * Nn;
    #pragma unroll
    for (int r = 0; r < 16; ++r) {                 // transpose+cvt 64n x 256c
        int g = r * 256 + t;
        int n = g & 63, cg = g >> 6;
        float f0 = xb[(size_t)(4*cg + 0) * Nn + n0 + n];
        float f1 = xb[(size_t)(4*cg + 1) * Nn + n0 + n];
        float f2 = xb[(size_t)(4*cg + 2) * Nn + n0 + n];
        float f3 = xb[(size_t)(4*cg + 3) * Nn + n0 + n];
        s16x4 p = { f2bf(f0), f2bf(f1), f2bf(f2), f2bf(f3) };
        *(s16x4*)&xT[n][4*cg] = p;
    }
    __syncthreads();

    f32x16 acc[4];
    #pragma unroll
    for (int s = 0; s < 4; ++s)
        #pragma unroll
        for (int r = 0; r < 16; ++r) acc[s][r] = 0.f;

    if (mat == 0) {
        // K: D[n][o] = sum_c xT[n][c] w[o][c]   (A = xT LDS, B = W8 chunked)
        const int mw = wid & 1, nwb = (wid >> 1) * 4;
        #pragma unroll 4
        for (int kk = 0; kk < 16; ++kk) {
            s16x8 a = *(const s16x8*)&xT[mw*32 + l31][kk*16 + h*8];
            #pragma unroll
            for (int s = 0; s < 4; ++s) {
                s16x8 bb = WFRAG(Wm, (nwb + s)*32 + l31, kk*2 + h);
                acc[s] = MFMA32(a, bb, acc[s]);
            }
        }
        // chunked store K8[o>>3][n][o&7]
        short* dst = KT + (size_t)b * Nn * Cc;
        #pragma unroll
        for (int s = 0; s < 4; ++s) {
            int o = (nwb + s)*32 + l31;
            float bia = bias[o];
            #pragma unroll
            for (int r = 0; r < 16; ++r) {
                int n = mw*32 + (r & 3) + 8*(r >> 2) + 4*h;
                dst[((size_t)(o >> 3) * Nn + n0 + n) * 8 + (o & 7)] = f2bf(acc[s][r] + bia);
            }
        }
    } else {
        // V: D[o][n] = sum_c w[o][c] xT[n][c]   (A = W8 chunked, B = xT LDS)
        #pragma unroll 4
        for (int kk = 0; kk < 16; ++kk) {
            s16x8 a0 = WFRAG(Wm, (wid*2 + 0)*32 + l31, kk*2 + h);
            s16x8 a1 = WFRAG(Wm, (wid*2 + 1)*32 + l31, kk*2 + h);
            s16x8 b0 = *(const s16x8*)&xT[ 0 + l31][kk*16 + h*8];
            s16x8 b1 = *(const s16x8*)&xT[32 + l31][kk*16 + h*8];
            acc[0] = MFMA32(a0, b0, acc[0]);
            acc[1] = MFMA32(a0, b1, acc[1]);
            acc[2] = MFMA32(a1, b0, acc[2]);
            acc[3] = MFMA32(a1, b1, acc[3]);
        }
        // V8[j>>3][c][j&7] chunked store
        short* dst = V + (size_t)b * Cc * Nn;
        #pragma unroll
        for (int sub = 0; sub < 4; ++sub) {
            int mc = sub >> 1, nc = sub & 1;
            int j = n0 + nc*32 + l31;
            #pragma unroll
            for (int r = 0; r < 16; ++r) {
                int o = (wid*2 + mc)*32 + (r & 3) + 8*(r >> 2) + 4*h;
                dst[((size_t)(j >> 3) * 256 + o) * 8 + (j & 7)] = f2bf(acc[sub][r] + bias[o]);
            }
        }
    }
}

// ---------------------------------------------------------------- attn (+Q, +proj fused)
// 512 thr: prologue computes the block's 64 Q-rows; waves 0-3 produce P
// (QK from register K-frags + exp), waves 4-7 consume (PV, reg-dbuf V);
// fused proj epilogue. No K LDS staging.
__global__ __launch_bounds__(512, 2) void attn_kernel(
    const short* __restrict__ KTg, const short* __restrict__ Vg,
    const short* __restrict__ Wg, const float* __restrict__ bq,
    const float* __restrict__ bp, const float* __restrict__ xg,
    float* __restrict__ outg)
{
    const int bid = blockIdx.x;
    const int b  = (bid & 7) >> 1;              // batch per XCD pair
    const int qt = ((bid >> 3) << 1) | (bid & 1);
    const int i0 = qt * 64;

    const int t = threadIdx.x, lane = t & 63, wid = t >> 6, h = lane >> 5, l31 = lane & 31;

    __shared__ alignas(16) short scr[32768];     // 64KB scratch: xTp/Fq/T/F
    __shared__ alignas(16) short Ps[2][64][72];
    __shared__ float lpart[2][64];
    __shared__ float linv[64];

    const short* Kb8 = KTg + (size_t)b * Nn * Cc; // chunked K8[c>>3][j][c&7]
    const short* Vb  = Vg  + (size_t)b * Cc * Nn; // chunked V8[j>>3][c][j&7]
    const float* xb  = xg + (size_t)b * Cc * Nn;

    const float SC = 0.09016844005f;            // C^-0.5 * log2(e)
    f32x16 oacc[4];

    // ---------------- prologue: compute Q[i0..i0+63][256] in-kernel
    // xT tile over scr, 16B-granule XOR swizzle: g16' = g16 ^ (row&15)
    {
        short* xTp = scr;                        // [64] rows x 512 B
        #pragma unroll
        for (int r = 0; r < 8; ++r) {            // transpose+cvt 64n x 256c
            int g = r * 512 + t;
            int n = g & 63, cg = g >> 6;         // c = 4*cg
            float f0 = xb[(size_t)(4*cg + 0) * Nn + i0 + n];
            float f1 = xb[(size_t)(4*cg + 1) * Nn + i0 + n];
            float f2 = xb[(size_t)(4*cg + 2) * Nn + i0 + n];
            float f3 = xb[(size_t)(4*cg + 3) * Nn + i0 + n];
            s16x4 p = { f2bf(f0), f2bf(f1), f2bf(f2), f2bf(f3) };
            int bcol = (((cg >> 1) ^ (n & 15)) << 4) + (cg & 1) * 8;
            *(s16x4*)((char*)xTp + n * 512 + bcol) = p;
        }
        __syncthreads();

        // Q-GEMM: D[n 0..63][o = wid*32+l31] = sum_c xT[n][c] Wq[o][c]
        const short* Wq = Wg;                    // mat 0 chunked
        f32x16 qa[2];
        #pragma unroll
        for (int s = 0; s < 2; ++s)
            #pragma unroll
            for (int r = 0; r < 16; ++r) qa[s][r] = 0.f;
        #pragma unroll 4
        for (int kk = 0; kk < 16; ++kk) {
            int gsw = ((kk*2 + h) ^ (l31 & 15)) << 4;
            s16x8 a0 = *(const s16x8*)((char*)xTp + ( 0 + l31) * 512 + gsw);
            s16x8 a1 = *(const s16x8*)((char*)xTp + (32 + l31) * 512 + gsw);
            s16x8 bb = WFRAG(Wq, wid*32 + l31, kk*2 + h);
            qa[0] = MFMA32(a0, bb, qa[0]);
            qa[1] = MFMA32(a1, bb, qa[1]);
        }
        // D + bq -> Fq (scr + 32KB), bf16, same granule swizzle
        short* Fq = scr + 16384;
        const int o = wid*32 + l31;
        const float bo = bq[o];
        #pragma unroll
        for (int mw2 = 0; mw2 < 2; ++mw2)
            #pragma unroll
            for (int r = 0; r < 16; ++r) {
                int n = mw2*32 + (r & 3) + 8*(r >> 2) + 4*h;
                int bcol = (((o >> 3) ^ (n & 15)) << 4) + (o & 7) * 2;
                *(short*)((char*)Fq + n * 512 + bcol) = f2bf(qa[mw2][r] + bo);
            }
    }
    __syncthreads();

    if (wid < 4) {
        // ---------------- producer: S^T = K Q^T, exp, P
        const int w4 = wid, mj = w4 >> 1, ni = w4 & 1;

        s16x8 qf[16];                            // from Fq (scr + 32KB)
        {
            const short* Fq = scr + 16384;
            const int qrow = ni*32 + l31;
            #pragma unroll
            for (int kc = 0; kc < 16; ++kc) {
                int bcol = ((kc*2 + h) ^ (qrow & 15)) << 4;
                qf[kc] = *(const s16x8*)((char*)Fq + qrow * 512 + bcol);
            }
        }
        float lacc = 0.f;
        const int rl = mj*32 + l31;             // A-frag row; (rl&31)==l31
        // K frag base: chunk (m*2+h), row rl -> byte ((m*2+h)*Nn + rl)*16
        const short* kbase = Kb8 + ((size_t)h * Nn + rl) * 8;

        s16x8 kf[16];
        for (int tt = 0; tt < 66; ++tt) {
            if (tt < 64) {
                const short* kp = kbase + (size_t)tt * 512;   // tile*64 rows *8
                #pragma unroll
                for (int m = 0; m < 16; ++m)
                    kf[m] = *(const s16x8*)(kp + (size_t)m * 65536);  // m*2*Nn*8

                f32x16 s0, s1;
                #pragma unroll
                for (int r = 0; r < 16; ++r) { s0[r] = 0.f; s1[r] = 0.f; }
                #pragma unroll
                for (int kc = 0; kc < 8; ++kc) {
                    s0 = MFMA32(kf[2*kc + 0], qf[2*kc + 0], s0);
                    s1 = MFMA32(kf[2*kc + 1], qf[2*kc + 1], s1);
                }
                float ps[16], lsum = 0.f;
                #pragma unroll
                for (int r = 0; r < 16; ++r) {
                    float e = exp2f((s0[r] + s1[r]) * SC);
                    ps[r] = e; lsum += e;
                }
                lsum += __shfl_xor(lsum, 32);
                lacc += lsum;
                const int ip = ni*32 + l31;
                const int pb = tt & 1;
                #pragma unroll
                for (int g = 0; g < 4; ++g) {
                    s16x4 pk = { f2bf(ps[4*g+0]), f2bf(ps[4*g+1]),
                                 f2bf(ps[4*g+2]), f2bf(ps[4*g+3]) };
                    *(s16x4*)&Ps[pb][ip][mj*32 + g*8 + 4*h] = pk;
                }
            }
            __syncthreads();
        }
        if (h == 0) lpart[mj][ni*32 + l31] = lacc;
    } else {
        // ---------------- consumer: O^T[c][i] += V[c][j] P[i][j]
        const int w2 = wid - 4;
        #pragma unroll
        for (int s = 0; s < 4; ++s)
            #pragma unroll
            for (int r = 0; r < 16; ++r) oacc[s][r] = 0.f;

        s16x8 vA[8], vB[8];
        // chunked V8: element (c,j) at ((j>>3)*256 + c)*8 + (j&7)
        const short* vc0 = Vb + (size_t)(w2*64 +  0 + l31) * 8 + h*2048;
        const short* vc1 = Vb + (size_t)(w2*64 + 32 + l31) * 8 + h*2048;

        for (int tp = 0; tp < 33; ++tp) {
            const int t0 = tp*2, t1 = t0 + 1;
            // even window t0: issue V tile t0 -> vA ; PV(t0-1) from vB + Ps[1]
            if (t0 < 64) {
                const size_t jc = (size_t)t0 * 8;   // j0>>3
                #pragma unroll
                for (int kj = 0; kj < 4; ++kj) {
                    vA[kj]   = *(const s16x8*)(vc0 + (jc + kj*2) * 2048);
                    vA[4+kj] = *(const s16x8*)(vc1 + (jc + kj*2) * 2048);
                }
            }
            if (t0 >= 1) {
                s16x8 p0[4], p1[4];
                #pragma unroll
                for (int kj = 0; kj < 4; ++kj) {
                    p0[kj] = *(const s16x8*)&Ps[1][ 0 + l31][kj*16 + h*8];
                    p1[kj] = *(const s16x8*)&Ps[1][32 + l31][kj*16 + h*8];
                }
                #pragma unroll
                for (int kj = 0; kj < 4; ++kj) {
                    oacc[0] = MFMA32(vB[kj],   p0[kj], oacc[0]);
                    oacc[1] = MFMA32(vB[kj],   p1[kj], oacc[1]);
                    oacc[2] = MFMA32(vB[4+kj], p0[kj], oacc[2]);
                    oacc[3] = MFMA32(vB[4+kj], p1[kj], oacc[3]);
                }
            }
            __syncthreads();
            // odd window t1: issue V tile t1 -> vB ; PV(t1-1) from vA + Ps[0]
            if (t1 < 64) {
                const size_t jc = (size_t)t1 * 8;
                #pragma unroll
                for (int kj = 0; kj < 4; ++kj) {
                    vB[kj]   = *(const s16x8*)(vc0 + (jc + kj*2) * 2048);
                    vB[4+kj] = *(const s16x8*)(vc1 + (jc + kj*2) * 2048);
                }
            }
            {
                s16x8 p0[4], p1[4];
                #pragma unroll
                for (int kj = 0; kj < 4; ++kj) {
                    p0[kj] = *(const s16x8*)&Ps[0][ 0 + l31][kj*16 + h*8];
                    p1[kj] = *(const s16x8*)&Ps[0][32 + l31][kj*16 + h*8];
                }
                #pragma unroll
                for (int kj = 0; kj < 4; ++kj) {
                    oacc[0] = MFMA32(vA[kj],   p0[kj], oacc[0]);
                    oacc[1] = MFMA32(vA[kj],   p1[kj], oacc[1]);
                    oacc[2] = MFMA32(vA[4+kj], p0[kj], oacc[2]);
                    oacc[3] = MFMA32(vA[4+kj], p1[kj], oacc[3]);
                }
            }
            __syncthreads();
        }
    }

    // ---------------- epilogue A: normalize, LDS-transpose O -> T[n][c]
    __syncthreads();
    if (t < 64) linv[t] = 1.0f / (lpart[0][t] + lpart[1][t]);
    __syncthreads();
    short (*T)[264] = (short(*)[264])scr;       // scratch
    if (wid >= 4) {
        const int w2 = wid - 4;
        #pragma unroll
        for (int sub = 0; sub < 4; ++sub) {
            int mc = sub >> 1, nc = sub & 1;
            int ip = nc*32 + l31;
            float rl2 = linv[ip];
            #pragma unroll
            for (int r = 0; r < 16; ++r) {
                int c = w2*64 + mc*32 + (r & 3) + 8*(r >> 2) + 4*h;
                T[ip][c] = f2bf(oacc[sub][r] * rl2);
            }
        }
    }
    __syncthreads();

    // ---------------- epilogue B: fused proj. D[n][o] = sum_c T[n][c] Wp[o][c]
    {
        const short* Wp = Wg + 3 * 65536;
        f32x16 acc2[2];
        #pragma unroll
        for (int s = 0; s < 2; ++s)
            #pragma unroll
            for (int r = 0; r < 16; ++r) acc2[s][r] = 0.f;

        #pragma unroll 4
        for (int kk = 0; kk < 16; ++kk) {
            s16x8 a0 = *(const s16x8*)&T[ 0 + l31][kk*16 + h*8];
            s16x8 a1 = *(const s16x8*)&T[32 + l31][kk*16 + h*8];
            s16x8 bb = WFRAG(Wp, wid*32 + l31, kk*2 + h);
            acc2[0] = MFMA32(a0, bb, acc2[0]);
            acc2[1] = MFMA32(a1, bb, acc2[1]);
        }
        __syncthreads();                         // all waves done reading T

        // bounce acc2 through XOR-swizzled fp32 tile F[n][o^(n&31)]
        float (*F)[256] = (float(*)[256])scr;    // 64n x 256o fp32 = 64 KB
        {
            const int o = wid*32 + l31;
            #pragma unroll
            for (int nh = 0; nh < 2; ++nh) {
                #pragma unroll
                for (int r = 0; r < 16; ++r) {
                    int n = nh*32 + (r & 3) + 8*(r >> 2) + 4*h;
                    F[n][o ^ (n & 31)] = acc2[nh][r];
                }
            }
        }
        __syncthreads();

        // coalesced residual+store: lanes take consecutive n, fixed o
        float* ob = outg + (size_t)b * Cc * Nn;
        #pragma unroll 8
        for (int it = 0; it < 32; ++it) {
            int o = it*8 + wid;
            size_t idx = (size_t)o * Nn + i0 + lane;
            ob[idx] = xb[idx] + F[lane][o ^ (lane & 31)] + bp[o];
        }
    }
}

// ---------------------------------------------------------------- launch
extern "C" void kernel_launch(void* const* d_in, const int* in_sizes, int n_in,
                              void* d_out, int out_size, void* d_ws, size_t ws_size,
                              hipStream_t stream)
{
    const float* x  = (const float*)d_in[0];
    const float* wq = (const float*)d_in[1];
    const float* bq = (const float*)d_in[2];
    const float* wk = (const float*)d_in[3];
    const float* bk = (const float*)d_in[4];
    const float* wv = (const float*)d_in[5];
    const float* bv = (const float*)d_in[6];
    const float* wp = (const float*)d_in[7];
    const float* bp = (const float*)d_in[8];

    const size_t elems = (size_t)4 * Nn * Cc;                 // 4.19 M / buffer
    const size_t need  = (2 * elems + 4 * 65536) * sizeof(short);  // 17.3 MiB
    if (ws_size < need) return;
    short* KT  = (short*)d_ws;                 // [b] chunked K8[c>>3][j][c&7]
    short* V   = KT + elems;                   // [b] chunked V8[j>>3][c][j&7]
    short* Wbf = V + elems;                    // 4 x chunked W8[c>>3][o][c&7]
    (void)in_sizes; (void)n_in; (void)out_size;

    wcvt_kernel<<<dim3(32, 4), 256, 0, stream>>>(wq, wk, wv, wp, Wbf);
    qkv_kernel<<<dim3(64, 4, 2), 256, 0, stream>>>(x, Wbf, bk, bv, KT, V);
    attn_kernel<<<dim3(256), 512, 0, stream>>>(KT, V, Wbf, bq, bp, x, (float*)d_out);
}

// Round 8
// 203.305 us; speedup vs baseline: 1.4361x; 1.4361x over previous
//
#include <hip/hip_runtime.h>
#include <hip/hip_bf16.h>

// NonLocalBlock B=4,C=256,H=W=64 (N=4096) — round 12.
//  r11 (K-in-registers) REVERTED: compiler collapsed kf to a rolling window
//  (VGPR=88) -> vmcnt waits immediately before MFMAs -> full memory latency
//  exposed per window (attn 192us, MfmaUtil 15%) + a tail double-add bug.
//  This round = r10 exactly, plus ONE change:
//   consumer waves use raw s_barrier (no vmcnt drain) so their V-register
//   double-buffer actually spans the barrier; producer keeps __syncthreads
//   (needs vmcnt(0) for global_load_lds K staging + lgkm for Ps publish).
// ws = KT | V8 | W8 = 17.3 MiB.

typedef __attribute__((ext_vector_type(4))) short s16x4;
typedef __attribute__((ext_vector_type(8))) short s16x8;
typedef __attribute__((ext_vector_type(16))) float f32x16;

#define MFMA32(a, b, c) __builtin_amdgcn_mfma_f32_32x32x16_bf16((a), (b), (c), 0, 0, 0)

constexpr int Cc = 256;
constexpr int Nn = 4096;

__device__ inline short f2bf(float f) {
    unsigned int u = __builtin_bit_cast(unsigned int, f);
    u = (u + 0x7fffu + ((u >> 16) & 1u)) >> 16;   // RNE
    return (short)u;
}

__device__ inline void gl_lds16(const short* g, short* l) {
    // async global->LDS, 16 B/lane; LDS dest = wave-uniform base + lane*16
    __builtin_amdgcn_global_load_lds((const unsigned int*)g, (unsigned int*)l, 16, 0, 0);
}

// 32x32x16 bf16 MFMA layouts (m74/m101-verified C/D; A/B symmetric k-map):
//   A[m=lane&31][k=(lane>>5)*8+j]   B[k=(lane>>5)*8+j][n=lane&31]
//   C/D: col=lane&31, row=(r&3)+8*(r>>2)+4*(lane>>5)

// W8 chunked fragment: row in [0,256), kc = chunk index (8 k elems each)
#define WFRAG(Wm, row, kc) (*(const s16x8*)&(Wm)[(size_t)(kc)*2048 + (size_t)(row)*8])

// ---------------------------------------------------------------- wcvt
// fp32 [o][c] -> bf16 chunked W8[c>>3][o][c&7]
__global__ __launch_bounds__(256, 4) void wcvt_kernel(
    const float* __restrict__ wq, const float* __restrict__ wk,
    const float* __restrict__ wv, const float* __restrict__ wp,
    short* __restrict__ W)
{
    const int m = blockIdx.y;
    const float* src = (m == 0) ? wq : (m == 1) ? wk : (m == 2) ? wv : wp;
    const int idx = (blockIdx.x * 256 + threadIdx.x) * 8;
    const int o = idx >> 8, c0 = idx & 255;
    float4 a = *(const float4*)(src + idx);
    float4 b = *(const float4*)(src + idx + 4);
    s16x8 p = { f2bf(a.x), f2bf(a.y), f2bf(a.z), f2bf(a.w),
                f2bf(b.x), f2bf(b.y), f2bf(b.z), f2bf(b.w) };
    *(s16x8*)(W + m * 65536 + ((size_t)(c0 >> 3) * 256 + o) * 8) = p;
}

// ---------------------------------------------------------------- qkv (K,V only)
// grid (64 n-tiles, 4 b, 2 mat), 256 thr. LDS xT tile 33.8 KB -> 4 blocks/CU.
__global__ __launch_bounds__(256, 4) void qkv_kernel(
    const float* __restrict__ x, const short* __restrict__ W,
    const float* __restrict__ bk, const float* __restrict__ bv,
    short* __restrict__ KT, short* __restrict__ V)
{
    const int nt = blockIdx.x, b = blockIdx.y, mat = blockIdx.z;  // 0=K 1=V
    const int n0 = nt * 64;
    const short* Wm = W + (mat + 1) * 65536;       // Wk at slot 1, Wv at slot 2
    const float* bias = (mat == 0) ? bk : bv;
    const int t = threadIdx.x, lane = t & 63, wid = t >> 6, h = lane >> 5, l31 = lane & 31;

    __shared__ alignas(16) short xT[64][264];      // x^T tile [n][c] bf16

    const float* xb = x + (size_t)b * Cc * Nn;
    #pragma unroll
    for (int r = 0; r < 16; ++r) {                 // transpose+cvt 64n x 256c
        int g = r * 256 + t;
        int n = g & 63, cg = g >> 6;
        float f0 = xb[(size_t)(4*cg + 0) * Nn + n0 + n];
        float f1 = xb[(size_t)(4*cg + 1) * Nn + n0 + n];
        float f2 = xb[(size_t)(4*cg + 2) * Nn + n0 + n];
        float f3 = xb[(size_t)(4*cg + 3) * Nn + n0 + n];
        s16x4 p = { f2bf(f0), f2bf(f1), f2bf(f2), f2bf(f3) };
        *(s16x4*)&xT[n][4*cg] = p;
    }
    __syncthreads();

    f32x16 acc[4];
    #pragma unroll
    for (int s = 0; s < 4; ++s)
        #pragma unroll
        for (int r = 0; r < 16; ++r) acc[s][r] = 0.f;

    if (mat == 0) {
        // K: D[n][o] = sum_c xT[n][c] w[o][c]   (A = xT LDS, B = W8 chunked)
        const int mw = wid & 1, nwb = (wid >> 1) * 4;
        #pragma unroll 4
        for (int kk = 0; kk < 16; ++kk) {
            s16x8 a = *(const s16x8*)&xT[mw*32 + l31][kk*16 + h*8];
            #pragma unroll
            for (int s = 0; s < 4; ++s) {
                s16x8 bb = WFRAG(Wm, (nwb + s)*32 + l31, kk*2 + h);
                acc[s] = MFMA32(a, bb, acc[s]);
            }
        }
        short* dst = KT + (size_t)b * Nn * Cc;     // row layout [n][c] for gl_lds
        #pragma unroll
        for (int s = 0; s < 4; ++s) {
            int o = (nwb + s)*32 + l31;
            float bia = bias[o];
            #pragma unroll
            for (int r = 0; r < 16; ++r) {
                int n = mw*32 + (r & 3) + 8*(r >> 2) + 4*h;
                dst[(size_t)(n0 + n) * Cc + o] = f2bf(acc[s][r] + bia);
            }
        }
    } else {
        // V: D[o][n] = sum_c w[o][c] xT[n][c]   (A = W8 chunked, B = xT LDS)
        #pragma unroll 4
        for (int kk = 0; kk < 16; ++kk) {
            s16x8 a0 = WFRAG(Wm, (wid*2 + 0)*32 + l31, kk*2 + h);
            s16x8 a1 = WFRAG(Wm, (wid*2 + 1)*32 + l31, kk*2 + h);
            s16x8 b0 = *(const s16x8*)&xT[ 0 + l31][kk*16 + h*8];
            s16x8 b1 = *(const s16x8*)&xT[32 + l31][kk*16 + h*8];
            acc[0] = MFMA32(a0, b0, acc[0]);
            acc[1] = MFMA32(a0, b1, acc[1]);
            acc[2] = MFMA32(a1, b0, acc[2]);
            acc[3] = MFMA32(a1, b1, acc[3]);
        }
        // V8[j>>3][c][j&7] chunked store
        short* dst = V + (size_t)b * Cc * Nn;
        #pragma unroll
        for (int sub = 0; sub < 4; ++sub) {
            int mc = sub >> 1, nc = sub & 1;
            int j = n0 + nc*32 + l31;
            #pragma unroll
            for (int r = 0; r < 16; ++r) {
                int o = (wid*2 + mc)*32 + (r & 3) + 8*(r >> 2) + 4*h;
                dst[((size_t)(j >> 3) * 256 + o) * 8 + (j & 7)] = f2bf(acc[sub][r] + bias[o]);
            }
        }
    }
}

// ---------------------------------------------------------------- attn (+Q, +proj fused)
// 512 thr: prologue computes the block's 64 Q-rows in-kernel; waves 0-3
// produce P (QK+exp, K via global_load_lds dbuf), waves 4-7 consume (PV,
// reg-dbuf V, RAW s_barrier — no vmcnt drain); fused proj epilogue.
__global__ __launch_bounds__(512, 2) void attn_kernel(
    const short* __restrict__ KTg, const short* __restrict__ Vg,
    const short* __restrict__ Wg, const float* __restrict__ bq,
    const float* __restrict__ bp, const float* __restrict__ xg,
    float* __restrict__ outg)
{
    const int bid = blockIdx.x;
    const int b  = (bid & 7) >> 1;              // batch per XCD pair
    const int qt = ((bid >> 3) << 1) | (bid & 1);
    const int i0 = qt * 64;

    const int t = threadIdx.x, lane = t & 63, wid = t >> 6, h = lane >> 5, l31 = lane & 31;

    __shared__ alignas(16) short Ks[2][64][256]; // swizzled: slot g holds granule g^(row&31)
    __shared__ alignas(16) short Ps[2][64][72];
    __shared__ float lpart[2][64];
    __shared__ float linv[64];
    short* KsF = &Ks[0][0][0];

    const short* Kb = KTg + (size_t)b * Nn * Cc;  // row layout [j][c]
    const short* Vb = Vg  + (size_t)b * Cc * Nn;  // chunked V8[j>>3][c][j&7]
    const float* xb = xg + (size_t)b * Cc * Nn;

    const float SC = 0.09016844005f;            // C^-0.5 * log2(e)
    f32x16 oacc[4];

    // ---------------- prologue: compute Q[i0..i0+63][256] in-kernel
    // xT tile over Ks[0], 16B-granule XOR swizzle: g16' = g16 ^ (row&15)
    {
        short* xTp = KsF;                        // [64] rows x 512 B
        #pragma unroll
        for (int r = 0; r < 8; ++r) {            // transpose+cvt 64n x 256c
            int g = r * 512 + t;
            int n = g & 63, cg = g >> 6;         // c = 4*cg
            float f0 = xb[(size_t)(4*cg + 0) * Nn + i0 + n];
            float f1 = xb[(size_t)(4*cg + 1) * Nn + i0 + n];
            float f2 = xb[(size_t)(4*cg + 2) * Nn + i0 + n];
            float f3 = xb[(size_t)(4*cg + 3) * Nn + i0 + n];
            s16x4 p = { f2bf(f0), f2bf(f1), f2bf(f2), f2bf(f3) };
            int bcol = (((cg >> 1) ^ (n & 15)) << 4) + (cg & 1) * 8;
            *(s16x4*)((char*)xTp + n * 512 + bcol) = p;
        }
        __syncthreads();

        // Q-GEMM: D[n 0..63][o = wid*32+l31] = sum_c xT[n][c] Wq[o][c]
        const short* Wq = Wg;                    // mat 0 chunked
        f32x16 qa[2];
        #pragma unroll
        for (int s = 0; s < 2; ++s)
            #pragma unroll
            for (int r = 0; r < 16; ++r) qa[s][r] = 0.f;
        #pragma unroll 4
        for (int kk = 0; kk < 16; ++kk) {
            int gsw = ((kk*2 + h) ^ (l31 & 15)) << 4;
            s16x8 a0 = *(const s16x8*)((char*)xTp + ( 0 + l31) * 512 + gsw);
            s16x8 a1 = *(const s16x8*)((char*)xTp + (32 + l31) * 512 + gsw);
            s16x8 bb = WFRAG(Wq, wid*32 + l31, kk*2 + h);
            qa[0] = MFMA32(a0, bb, qa[0]);
            qa[1] = MFMA32(a1, bb, qa[1]);
        }
        // D + bq -> Fq (over Ks[1]), bf16, same granule swizzle
        short* Fq = KsF + 16384;
        const int o = wid*32 + l31;
        const float bo = bq[o];
        #pragma unroll
        for (int mw2 = 0; mw2 < 2; ++mw2)
            #pragma unroll
            for (int r = 0; r < 16; ++r) {
                int n = mw2*32 + (r & 3) + 8*(r >> 2) + 4*h;
                int bcol = (((o >> 3) ^ (n & 15)) << 4) + (o & 7) * 2;
                *(short*)((char*)Fq + n * 512 + bcol) = f2bf(qa[mw2][r] + bo);
            }
    }
    __syncthreads();

    if (wid < 4) {
        // ---------------- producer: S^T = K Q^T, exp, P
        const int w4 = wid, mj = w4 >> 1, ni = w4 & 1;

        s16x8 qf[16];                            // from Fq (Ks[1] area)
        {
            const short* Fq = KsF + 16384;
            const int qrow = ni*32 + l31;
            #pragma unroll
            for (int kc = 0; kc < 16; ++kc) {
                int bcol = ((kc*2 + h) ^ (qrow & 15)) << 4;
                qf[kc] = *(const s16x8*)((char*)Fq + qrow * 512 + bcol);
            }
        }
        float lacc = 0.f;
        const int rl = mj*32 + l31;             // A-frag row; (rl&31)==l31

        for (int tt = 0; tt < 66; ++tt) {
            if (tt < 64) {                       // stage K tile tt (async DMA)
                const int kb = tt & 1;
                #pragma unroll
                for (int it = 0; it < 8; ++it) {
                    int r = (w4*8 + it)*2 + (lane >> 5);
                    int g = l31 ^ (r & 31);
                    const short* gp = Kb + (size_t)(tt*64 + r) * Cc + g*8;
                    short* lp = KsF + kb*16384 + (w4*8 + it)*512;  // wave-uniform
                    gl_lds16(gp, lp);
                }
            }
            if (tt >= 1 && tt < 65) {
                const int jt = tt - 1, kb = jt & 1;
                const short* abase = KsF + kb*16384 + rl*256;
                f32x16 s0, s1;
                #pragma unroll
                for (int r = 0; r < 16; ++r) { s0[r] = 0.f; s1[r] = 0.f; }
                #pragma unroll
                for (int kc = 0; kc < 8; ++kc) {
                    s16x8 a0 = *(const s16x8*)(abase + (((kc*4 + 0 + h) ^ l31) << 3));
                    s16x8 a1 = *(const s16x8*)(abase + (((kc*4 + 2 + h) ^ l31) << 3));
                    s0 = MFMA32(a0, qf[2*kc + 0], s0);
                    s1 = MFMA32(a1, qf[2*kc + 1], s1);
                }
                float ps[16], lsum = 0.f;
                #pragma unroll
                for (int r = 0; r < 16; ++r) {
                    float e = exp2f((s0[r] + s1[r]) * SC);
                    ps[r] = e; lsum += e;
                }
                lsum += __shfl_xor(lsum, 32);
                lacc += lsum;
                const int ip = ni*32 + l31;
                #pragma unroll
                for (int g = 0; g < 4; ++g) {
                    s16x4 pk = { f2bf(ps[4*g+0]), f2bf(ps[4*g+1]),
                                 f2bf(ps[4*g+2]), f2bf(ps[4*g+3]) };
                    *(s16x4*)&Ps[kb][ip][mj*32 + g*8 + 4*h] = pk;
                }
            }
            __syncthreads();                     // producer: full drain (Ks + Ps publish)
        }
        if (h == 0) lpart[mj][ni*32 + l31] = lacc;
    } else {
        // ---------------- consumer: O^T[c][i] += V[c][j] P[i][j]
        const int w2 = wid - 4;
        #pragma unroll
        for (int s = 0; s < 4; ++s)
            #pragma unroll
            for (int r = 0; r < 16; ++r) oacc[s][r] = 0.f;

        s16x8 vA[8], vB[8];
        // chunked V8: element (c,j) at ((j>>3)*256 + c)*8 + (j&7)
        const short* vc0 = Vb + (size_t)(w2*64 +  0 + l31) * 8 + h*2048;
        const short* vc1 = Vb + (size_t)(w2*64 + 32 + l31) * 8 + h*2048;

        for (int tp = 0; tp < 33; ++tp) {
            const int t0 = tp*2, t1 = t0 + 1;
            // even step t0: issue tile t0-1 -> vA ; consume tile t0-2 from vB
            if (t0 >= 1 && t0 <= 64) {
                const size_t jc = (size_t)(t0 - 1) * 8;   // j0>>3
                #pragma unroll
                for (int kj = 0; kj < 4; ++kj) {
                    vA[kj]   = *(const s16x8*)(vc0 + (jc + kj*2) * 2048);
                    vA[4+kj] = *(const s16x8*)(vc1 + (jc + kj*2) * 2048);
                }
            }
            if (t0 >= 2) {
                const int pb = (t0 - 2) & 1;
                s16x8 p0[4], p1[4];
                #pragma unroll
                for (int kj = 0; kj < 4; ++kj) {
                    p0[kj] = *(const s16x8*)&Ps[pb][ 0 + l31][kj*16 + h*8];
                    p1[kj] = *(const s16x8*)&Ps[pb][32 + l31][kj*16 + h*8];
                }
                #pragma unroll
                for (int kj = 0; kj < 4; ++kj) {
                    oacc[0] = MFMA32(vB[kj],   p0[kj], oacc[0]);
                    oacc[1] = MFMA32(vB[kj],   p1[kj], oacc[1]);
                    oacc[2] = MFMA32(vB[4+kj], p0[kj], oacc[2]);
                    oacc[3] = MFMA32(vB[4+kj], p1[kj], oacc[3]);
                }
            }
            // raw barrier: keep this window's V loads in flight (compiler
            // inserts the counted vmcnt at next window's first use of vA/vB)
            asm volatile("s_barrier" ::: "memory");
            // odd step t1: issue tile t1-1 -> vB ; consume tile t1-2 from vA
            if (t1 <= 64) {
                const size_t jc = (size_t)(t1 - 1) * 8;
                #pragma unroll
                for (int kj = 0; kj < 4; ++kj) {
                    vB[kj]   = *(const s16x8*)(vc0 + (jc + kj*2) * 2048);
                    vB[4+kj] = *(const s16x8*)(vc1 + (jc + kj*2) * 2048);
                }
            }
            if (t1 >= 2) {
                const int pb = (t1 - 2) & 1;
                s16x8 p0[4], p1[4];
                #pragma unroll
                for (int kj = 0; kj < 4; ++kj) {
                    p0[kj] = *(const s16x8*)&Ps[pb][ 0 + l31][kj*16 + h*8];
                    p1[kj] = *(const s16x8*)&Ps[pb][32 + l31][kj*16 + h*8];
                }
                #pragma unroll
                for (int kj = 0; kj < 4; ++kj) {
                    oacc[0] = MFMA32(vA[kj],   p0[kj], oacc[0]);
                    oacc[1] = MFMA32(vA[kj],   p1[kj], oacc[1]);
                    oacc[2] = MFMA32(vA[4+kj], p0[kj], oacc[2]);
                    oacc[3] = MFMA32(vA[4+kj], p1[kj], oacc[3]);
                }
            }
            asm volatile("s_barrier" ::: "memory");
        }
    }

    // ---------------- epilogue A: normalize, LDS-transpose O -> T[n][c]
    __syncthreads();
    if (t < 64) linv[t] = 1.0f / (lpart[0][t] + lpart[1][t]);
    __syncthreads();
    short (*T)[264] = (short(*)[264])KsF;       // scratch over Ks
    if (wid >= 4) {
        const int w2 = wid - 4;
        #pragma unroll
        for (int sub = 0; sub < 4; ++sub) {
            int mc = sub >> 1, nc = sub & 1;
            int ip = nc*32 + l31;
            float rl2 = linv[ip];
            #pragma unroll
            for (int r = 0; r < 16; ++r) {
                int c = w2*64 + mc*32 + (r & 3) + 8*(r >> 2) + 4*h;
                T[ip][c] = f2bf(oacc[sub][r] * rl2);
            }
        }
    }
    __syncthreads();

    // ---------------- epilogue B: fused proj. D[n][o] = sum_c T[n][c] Wp[o][c]
    {
        const short* Wp = Wg + 3 * 65536;
        f32x16 acc2[2];
        #pragma unroll
        for (int s = 0; s < 2; ++s)
            #pragma unroll
            for (int r = 0; r < 16; ++r) acc2[s][r] = 0.f;

        #pragma unroll 4
        for (int kk = 0; kk < 16; ++kk) {
            s16x8 a0 = *(const s16x8*)&T[ 0 + l31][kk*16 + h*8];
            s16x8 a1 = *(const s16x8*)&T[32 + l31][kk*16 + h*8];
            s16x8 bb = WFRAG(Wp, wid*32 + l31, kk*2 + h);
            acc2[0] = MFMA32(a0, bb, acc2[0]);
            acc2[1] = MFMA32(a1, bb, acc2[1]);
        }
        __syncthreads();                         // all waves done reading T

        // bounce acc2 through XOR-swizzled fp32 tile F[n][o^(n&31)]
        float (*F)[256] = (float(*)[256])KsF;    // 64n x 256o fp32 = 64 KB
        {
            const int o = wid*32 + l31;
            #pragma unroll
            for (int nh = 0; nh < 2; ++nh) {
                #pragma unroll
                for (int r = 0; r < 16; ++r) {
                    int n = nh*32 + (r & 3) + 8*(r >> 2) + 4*h;
                    F[n][o ^ (n & 31)] = acc2[nh][r];
                }
            }
        }
        __syncthreads();

        // coalesced residual+store: lanes take consecutive n, fixed o
        float* ob = outg + (size_t)b * Cc * Nn;
        #pragma unroll 8
        for (int it = 0; it < 32; ++it) {
            int o = it*8 + wid;
            size_t idx = (size_t)o * Nn + i0 + lane;
            ob[idx] = xb[idx] + F[lane][o ^ (lane & 31)] + bp[o];
        }
    }
}

// ---------------------------------------------------------------- launch
extern "C" void kernel_launch(void* const* d_in, const int* in_sizes, int n_in,
                              void* d_out, int out_size, void* d_ws, size_t ws_size,
                              hipStream_t stream)
{
    const float* x  = (const float*)d_in[0];
    const float* wq = (const float*)d_in[1];
    const float* bq = (const float*)d_in[2];
    const float* wk = (const float*)d_in[3];
    const float* bk = (const float*)d_in[4];
    const float* wv = (const float*)d_in[5];
    const float* bv = (const float*)d_in[6];
    const float* wp = (const float*)d_in[7];
    const float* bp = (const float*)d_in[8];

    const size_t elems = (size_t)4 * Nn * Cc;                 // 4.19 M / buffer
    const size_t need  = (2 * elems + 4 * 65536) * sizeof(short);  // 17.3 MiB
    if (ws_size < need) return;
    short* KT  = (short*)d_ws;                 // [b][n][c] bf16
    short* V   = KT + elems;                   // [b] chunked V8[j>>3][c][j&7]
    short* Wbf = V + elems;                    // 4 x chunked W8[c>>3][o][c&7]
    (void)in_sizes; (void)n_in; (void)out_size;

    wcvt_kernel<<<dim3(32, 4), 256, 0, stream>>>(wq, wk, wv, wp, Wbf);
    qkv_kernel<<<dim3(64, 4, 2), 256, 0, stream>>>(x, Wbf, bk, bv, KT, V);
    attn_kernel<<<dim3(256), 512, 0, stream>>>(KT, V, Wbf, bq, bp, x, (float*)d_out);
}